// Round 12
// baseline (332.743 us; speedup 1.0000x reference)
//
#include <hip/hip_runtime.h>
#include <hip/hip_bf16.h>
#include <hip/hip_cooperative_groups.h>
#include <math.h>

namespace cg = cooperative_groups;

#define LATENT 256
#define HIDDEN 512
#define NODE_F 128
#define MAX_NODES 50
#define NPAIRS 1225        // 50*49/2
#define BATCH 128
#define NODE_OUT 6400      // MAX_NODES*NODE_F
#define MTILE 64           // edge rows per tile
#define TPB 10             // tiles per block (20 tiles/batch = 2 blocks/batch)
#define NBLK 256           // cooperative grid (1 block/CU)
#define NTHR 512

typedef __attribute__((ext_vector_type(8))) short short8;
typedef __attribute__((ext_vector_type(4))) float float4v;

union S8U { short8 s; unsigned int u[4]; };

__device__ __forceinline__ float bf2f(ushort u) {
    union { unsigned int i; float f; } v; v.i = ((unsigned int)u) << 16; return v.f;
}
__device__ __forceinline__ ushort f2bf(float f) {
    union { unsigned int i; float f; } v; v.f = f;
    unsigned int r = v.i + 0x7fffu + ((v.i >> 16) & 1u);   // RNE
    return (ushort)(r >> 16);
}
__device__ __forceinline__ unsigned int pk_bf16(float f0, float f1) {
    __hip_bfloat162 p = __float22bfloat162_rn(float2{f0, f1});   // v_cvt_pk_bf16_f32 (RNE)
    unsigned int w; __builtin_memcpy(&w, &p, 4); return w;
}
__device__ __forceinline__ float sigmoidf(float x) {
    return 1.0f / (1.0f + __expf(-x));
}

// ======================= the single cooperative mega-kernel =======================
__global__ __launch_bounds__(512, 2) void k_all(
    const float* __restrict__ z,   const float* __restrict__ nw1, const float* __restrict__ nb1,
    const float* __restrict__ nw2, const float* __restrict__ nb2, const float* __restrict__ nw3,
    const float* __restrict__ nb3, const float* __restrict__ ew1, const float* __restrict__ eb1,
    const float* __restrict__ ew2, const float* __restrict__ eb2, const float* __restrict__ ew3,
    const float* __restrict__ eb3,
    int* __restrict__ ptab, ushort* __restrict__ h2b, ushort* __restrict__ nf,
    ushort* __restrict__ ew2T, ushort* __restrict__ wijT, ushort* __restrict__ nw3T,
    float* __restrict__ Zc, ushort* __restrict__ UV,
    float* __restrict__ node_probs, float* __restrict__ out_edges)
{
    __shared__ __align__(16) char lds[140288];
    cg::grid_group gg = cg::this_grid();

    int tid = threadIdx.x;
    int blk = blockIdx.x;
    int wave = tid >> 6, lane = tid & 63;
    int m16 = lane & 15, quad = lane >> 4;

    // ================= phase 1: all prep =================
    // elementwise: ew2T (131072), wijT (131072), ptab (1225)
    for (int t = blk * NTHR + tid; t < 131072 + 131072 + NPAIRS; t += NBLK * NTHR) {
        if (t < 131072) {
            int n = t >> 9, k = t & 511;
            ew2T[t] = f2bf(ew2[k * 256 + n]);
        } else if (t < 262144) {
            int u = t - 131072;
            int n = u >> 7, k = u & 127;
            float s = (n < 512) ? ew1[(256 + k) * 512 + n] : ew1[(384 + k) * 512 + (n - 512)];
            wijT[u] = f2bf(s);
        } else {
            int p = t - 262144;
            int i = 0, off = 0;
            while (p - off >= MAX_NODES - 1 - i) { off += MAX_NODES - 1 - i; ++i; }
            ptab[p] = (i << 8) | (i + 1 + (p - off));
        }
    }
    // LDS jobs: [0,800) nw3T 64x64 tile transpose; [800,928) Zc; [928,1056) fused node MLP
    {
        float* smem = (float*)lds;
        for (int j = blk; j < 1056; j += NBLK) {
            if (j < 800) {
                int k0 = (j & 7) * 64;
                int n0 = (j >> 3) * 64;
                int tx = tid & 63, ty = tid >> 6;   // 64 x 8
#pragma unroll
                for (int r = 0; r < 8; r++) {
                    int row = r * 8 + ty;
                    smem[row * 65 + tx] = nw3[(k0 + row) * NODE_OUT + n0 + tx];
                }
                __syncthreads();
#pragma unroll
                for (int c = 0; c < 8; c++) {
                    int n = c * 8 + ty;
                    nw3T[(size_t)(n0 + n) * HIDDEN + k0 + tx] = f2bf(smem[tx * 65 + n]);
                }
            } else if (j < 928) {
                int r = j - 800;
                if (tid < 256) smem[tid] = z[r * LATENT + tid];
                __syncthreads();
                float acc = 0.f;
#pragma unroll 8
                for (int k = 0; k < LATENT; k++) acc += smem[k] * ew1[k * HIDDEN + tid];
                Zc[r * HIDDEN + tid] = acc + eb1[tid];
            } else {
                int r = j - 928;
                float* hs = smem + 256;
                if (tid < 256) smem[tid] = z[r * LATENT + tid];
                __syncthreads();
                float a = 0.f;
#pragma unroll 8
                for (int k = 0; k < LATENT; k++) a += smem[k] * nw1[k * HIDDEN + tid];
                hs[tid] = fmaxf(a + nb1[tid], 0.f);
                __syncthreads();
                float acc = 0.f;
#pragma unroll 8
                for (int k = 0; k < HIDDEN; k++) acc += hs[k] * nw2[k * HIDDEN + tid];
                h2b[r * HIDDEN + tid] = f2bf(fmaxf(acc + nb2[tid], 0.f));
            }
            __syncthreads();
        }
    }
    gg.sync();

    // ================= phase 2: node layer 3 (MFMA) -> probs + nf =================
    if (blk < 100) {
        int n0 = blk * 64;
        int col = n0 + (wave & 3) * 16 + m16;
        int m0 = (wave >> 2) * 64;

        float4v acc[4];
#pragma unroll
        for (int mt = 0; mt < 4; mt++) acc[mt] = (float4v)(0.f);

        const ushort* bb = nw3T + (size_t)col * HIDDEN;
#pragma unroll
        for (int it = 0; it < 16; ++it) {
            int kk = it * 32 + quad * 8;
            short8 b = *(const short8*)(bb + kk);
#pragma unroll
            for (int mt = 0; mt < 4; mt++) {
                short8 a = *(const short8*)(h2b + (m0 + mt * 16 + m16) * HIDDEN + kk);
                acc[mt] = __builtin_amdgcn_mfma_f32_16x16x32_bf16(a, b, acc[mt], 0, 0, 0);
            }
        }
        float bias = nb3[col];
#pragma unroll
        for (int mt = 0; mt < 4; mt++)
#pragma unroll
            for (int t = 0; t < 4; t++) {
                int row = m0 + mt * 16 + quad * 4 + t;
                float v = acc[mt][t] + bias;
                node_probs[(size_t)row * NODE_OUT + col] = sigmoidf(v);
                nf[(size_t)row * NODE_OUT + col] = f2bf(v);
            }
    }
    gg.sync();

    // ================= phase 3: UV = nf @ [W_i|W_j] =================
    if (blk < 200) {
        int bm = blk >> 1, bn = blk & 1;
        int base = bn * 512 + wave * 64;
        int r0 = bm * 64;

        float4v acc[4][4];
#pragma unroll
        for (int mt = 0; mt < 4; mt++)
#pragma unroll
            for (int nt = 0; nt < 4; nt++) acc[mt][nt] = (float4v)(0.f);

#pragma unroll
        for (int k0 = 0; k0 < NODE_F; k0 += 32) {
            int kk = k0 + quad * 8;
            short8 a0 = *(const short8*)(nf + (r0 + m16) * NODE_F + kk);
            short8 a1 = *(const short8*)(nf + (r0 + 16 + m16) * NODE_F + kk);
            short8 a2 = *(const short8*)(nf + (r0 + 32 + m16) * NODE_F + kk);
            short8 a3 = *(const short8*)(nf + (r0 + 48 + m16) * NODE_F + kk);
#pragma unroll
            for (int nt = 0; nt < 4; nt++) {
                int n = base + nt * 16 + m16;
                short8 b = *(const short8*)(wijT + n * NODE_F + kk);
                acc[0][nt] = __builtin_amdgcn_mfma_f32_16x16x32_bf16(a0, b, acc[0][nt], 0, 0, 0);
                acc[1][nt] = __builtin_amdgcn_mfma_f32_16x16x32_bf16(a1, b, acc[1][nt], 0, 0, 0);
                acc[2][nt] = __builtin_amdgcn_mfma_f32_16x16x32_bf16(a2, b, acc[2][nt], 0, 0, 0);
                acc[3][nt] = __builtin_amdgcn_mfma_f32_16x16x32_bf16(a3, b, acc[3][nt], 0, 0, 0);
            }
        }
#pragma unroll
        for (int nt = 0; nt < 4; nt++) {
            int colg = base + nt * 16 + m16;
#pragma unroll
            for (int mt = 0; mt < 4; mt++)
#pragma unroll
                for (int t = 0; t < 4; t++) {
                    int rr = r0 + mt * 16 + quad * 4 + t;
                    UV[(size_t)rr * 1024 + colg] = f2bf(acc[mt][nt][t]);
                }
        }
    }
    gg.sync();

    // ================= phase 4: fused edge (persistent-B, TPB=10) =================
    {
        ushort (*h1)[MTILE][HIDDEN + 8] = (ushort (*)[MTILE][HIDDEN + 8])lds;  // [2], 133120 B
        float (*partE)[8] = (float (*)[8])(lds + 133120);                      // 2048 B
        int (*uo5)[MTILE] = (int (*)[MTILE])(lds + 135168);                    // 2560 B
        int (*vo5)[MTILE] = (int (*)[MTILE])(lds + 137728);                    // 2560 B

        int b   = blk >> 1;
        int ti0 = (blk & 1) * TPB;

        if (tid < MTILE) {
#pragma unroll
            for (int t = 0; t < TPB; t++) {
                int p = (ti0 + t) * MTILE + tid;
                if (p >= NPAIRS) p = NPAIRS - 1;
                int ij = ptab[p];
                uo5[t][tid] = (b * MAX_NODES + (ij >> 8)) * 1024;
                vo5[t][tid] = (b * MAX_NODES + (ij & 255)) * 1024 + 512;
            }
        }

        int c8 = lane * 8;
        int kk0 = quad * 8;

        float4v zA = *(const float4v*)(Zc + b * HIDDEN + c8);
        float4v zB = *(const float4v*)(Zc + b * HIDDEN + c8 + 4);

        const ushort* bb0 = ew2T + (wave * 32 + m16) * HIDDEN;
        const ushort* bb1 = ew2T + (wave * 32 + 16 + m16) * HIDDEN;
        short8 Breg[16][2];
#pragma unroll
        for (int kc = 0; kc < 16; kc++) {
            Breg[kc][0] = *(const short8*)(bb0 + kc * 32 + kk0);
            Breg[kc][1] = *(const short8*)(bb1 + kc * 32 + kk0);
        }
        float eb2v[2], ew3v[2];
        eb2v[0] = eb2[wave * 32 + m16];      eb2v[1] = eb2[wave * 32 + 16 + m16];
        ew3v[0] = ew3[wave * 32 + m16];      ew3v[1] = ew3[wave * 32 + 16 + m16];

        __syncthreads();   // uo5/vo5 ready

        // assemble tile 0 into buf 0
#pragma unroll
        for (int rr = 0; rr < 8; rr++) {
            int r = wave * 8 + rr;
            short8 u8 = *(const short8*)(UV + uo5[0][r] + c8);
            short8 v8 = *(const short8*)(UV + vo5[0][r] + c8);
            S8U hh;
#pragma unroll
            for (int e2 = 0; e2 < 4; e2++) {
                float z0 = (e2 < 2) ? zA[e2 * 2] : zB[e2 * 2 - 4];
                float z1 = (e2 < 2) ? zA[e2 * 2 + 1] : zB[e2 * 2 - 3];
                float f0 = fmaxf(z0 + bf2f((ushort)u8[e2 * 2]) + bf2f((ushort)v8[e2 * 2]), 0.f);
                float f1 = fmaxf(z1 + bf2f((ushort)u8[e2 * 2 + 1]) + bf2f((ushort)v8[e2 * 2 + 1]), 0.f);
                hh.u[e2] = pk_bf16(f0, f1);
            }
            *(short8*)&h1[0][r][c8] = hh.s;
        }
        __syncthreads();

        for (int t = 0; t < TPB; t++) {
            int cur = t & 1, nxt = cur ^ 1;
            bool hasNext = (t + 1 < TPB);

            float4v acc2[4][2];
#pragma unroll
            for (int mt = 0; mt < 4; mt++)
#pragma unroll
                for (int nt = 0; nt < 2; nt++) acc2[mt][nt] = (float4v)(0.f);

            short8 uu[4], vv[4];
            if (hasNext) {
#pragma unroll
                for (int rr = 0; rr < 4; rr++) {
                    int r = wave * 8 + rr;
                    uu[rr] = *(const short8*)(UV + uo5[t + 1][r] + c8);
                    vv[rr] = *(const short8*)(UV + vo5[t + 1][r] + c8);
                }
            }
#pragma unroll
            for (int it = 0; it < 8; ++it) {
                int kk = it * 32 + kk0;
                short8 a0 = *(const short8*)&h1[cur][m16][kk];
                short8 a1 = *(const short8*)&h1[cur][16 + m16][kk];
                short8 a2 = *(const short8*)&h1[cur][32 + m16][kk];
                short8 a3 = *(const short8*)&h1[cur][48 + m16][kk];
                acc2[0][0] = __builtin_amdgcn_mfma_f32_16x16x32_bf16(a0, Breg[it][0], acc2[0][0], 0, 0, 0);
                acc2[1][0] = __builtin_amdgcn_mfma_f32_16x16x32_bf16(a1, Breg[it][0], acc2[1][0], 0, 0, 0);
                acc2[2][0] = __builtin_amdgcn_mfma_f32_16x16x32_bf16(a2, Breg[it][0], acc2[2][0], 0, 0, 0);
                acc2[3][0] = __builtin_amdgcn_mfma_f32_16x16x32_bf16(a3, Breg[it][0], acc2[3][0], 0, 0, 0);
                acc2[0][1] = __builtin_amdgcn_mfma_f32_16x16x32_bf16(a0, Breg[it][1], acc2[0][1], 0, 0, 0);
                acc2[1][1] = __builtin_amdgcn_mfma_f32_16x16x32_bf16(a1, Breg[it][1], acc2[1][1], 0, 0, 0);
                acc2[2][1] = __builtin_amdgcn_mfma_f32_16x16x32_bf16(a2, Breg[it][1], acc2[2][1], 0, 0, 0);
                acc2[3][1] = __builtin_amdgcn_mfma_f32_16x16x32_bf16(a3, Breg[it][1], acc2[3][1], 0, 0, 0);
            }
            if (hasNext) {
#pragma unroll
                for (int rr = 0; rr < 4; rr++) {
                    int r = wave * 8 + rr;
                    S8U hh;
#pragma unroll
                    for (int e2 = 0; e2 < 4; e2++) {
                        float z0 = (e2 < 2) ? zA[e2 * 2] : zB[e2 * 2 - 4];
                        float z1 = (e2 < 2) ? zA[e2 * 2 + 1] : zB[e2 * 2 - 3];
                        float f0 = fmaxf(z0 + bf2f((ushort)uu[rr][e2 * 2]) + bf2f((ushort)vv[rr][e2 * 2]), 0.f);
                        float f1 = fmaxf(z1 + bf2f((ushort)uu[rr][e2 * 2 + 1]) + bf2f((ushort)vv[rr][e2 * 2 + 1]), 0.f);
                        hh.u[e2] = pk_bf16(f0, f1);
                    }
                    *(short8*)&h1[nxt][r][c8] = hh.s;
                }
#pragma unroll
                for (int rr = 0; rr < 4; rr++) {
                    int r = wave * 8 + 4 + rr;
                    uu[rr] = *(const short8*)(UV + uo5[t + 1][r] + c8);
                    vv[rr] = *(const short8*)(UV + vo5[t + 1][r] + c8);
                }
            }
#pragma unroll
            for (int it = 8; it < 16; ++it) {
                int kk = it * 32 + kk0;
                short8 a0 = *(const short8*)&h1[cur][m16][kk];
                short8 a1 = *(const short8*)&h1[cur][16 + m16][kk];
                short8 a2 = *(const short8*)&h1[cur][32 + m16][kk];
                short8 a3 = *(const short8*)&h1[cur][48 + m16][kk];
                acc2[0][0] = __builtin_amdgcn_mfma_f32_16x16x32_bf16(a0, Breg[it][0], acc2[0][0], 0, 0, 0);
                acc2[1][0] = __builtin_amdgcn_mfma_f32_16x16x32_bf16(a1, Breg[it][0], acc2[1][0], 0, 0, 0);
                acc2[2][0] = __builtin_amdgcn_mfma_f32_16x16x32_bf16(a2, Breg[it][0], acc2[2][0], 0, 0, 0);
                acc2[3][0] = __builtin_amdgcn_mfma_f32_16x16x32_bf16(a3, Breg[it][0], acc2[3][0], 0, 0, 0);
                acc2[0][1] = __builtin_amdgcn_mfma_f32_16x16x32_bf16(a0, Breg[it][1], acc2[0][1], 0, 0, 0);
                acc2[1][1] = __builtin_amdgcn_mfma_f32_16x16x32_bf16(a1, Breg[it][1], acc2[1][1], 0, 0, 0);
                acc2[2][1] = __builtin_amdgcn_mfma_f32_16x16x32_bf16(a2, Breg[it][1], acc2[2][1], 0, 0, 0);
                acc2[3][1] = __builtin_amdgcn_mfma_f32_16x16x32_bf16(a3, Breg[it][1], acc2[3][1], 0, 0, 0);
            }
            if (hasNext) {
#pragma unroll
                for (int rr = 0; rr < 4; rr++) {
                    int r = wave * 8 + 4 + rr;
                    S8U hh;
#pragma unroll
                    for (int e2 = 0; e2 < 4; e2++) {
                        float z0 = (e2 < 2) ? zA[e2 * 2] : zB[e2 * 2 - 4];
                        float z1 = (e2 < 2) ? zA[e2 * 2 + 1] : zB[e2 * 2 - 3];
                        float f0 = fmaxf(z0 + bf2f((ushort)uu[rr][e2 * 2]) + bf2f((ushort)vv[rr][e2 * 2]), 0.f);
                        float f1 = fmaxf(z1 + bf2f((ushort)uu[rr][e2 * 2 + 1]) + bf2f((ushort)vv[rr][e2 * 2 + 1]), 0.f);
                        hh.u[e2] = pk_bf16(f0, f1);
                    }
                    *(short8*)&h1[nxt][r][c8] = hh.s;
                }
            }

            // epilogue: fused relu + partial dot (32 cols) via shfl-reduce
#pragma unroll
            for (int mt = 0; mt < 4; mt++)
#pragma unroll
                for (int tt = 0; tt < 4; tt++) {
                    float s = 0.f;
#pragma unroll
                    for (int nt = 0; nt < 2; nt++)
                        s += fmaxf(acc2[mt][nt][tt] + eb2v[nt], 0.f) * ew3v[nt];
                    s += __shfl_xor(s, 1);
                    s += __shfl_xor(s, 2);
                    s += __shfl_xor(s, 4);
                    s += __shfl_xor(s, 8);
                    if (m16 == 0) partE[mt * 16 + quad * 4 + tt][wave] = s;
                }
            __syncthreads();

            if (tid < MTILE) {
                int p = (ti0 + t) * MTILE + tid;
                if (p < NPAIRS) {
                    float v = eb3[0];
#pragma unroll
                    for (int w = 0; w < 8; w++) v += partE[tid][w];
                    out_edges[b * NPAIRS + p] = sigmoidf(v);
                }
            }
            __syncthreads();
        }
    }
}

// ======================= fallback path (R11 kernels, unchanged) =======================
#define TR3_B0   0
#define PREP_B0  800
#define ZC_B0    1824
#define ND_B0    2080
#define PT_B0    2336
#define PREPK_NB 2341

__global__ __launch_bounds__(256) void k_prep_all(
    const float* __restrict__ nw3, ushort* __restrict__ nw3T,
    const float* __restrict__ ew1, const float* __restrict__ ew2,
    ushort* __restrict__ ew2T, ushort* __restrict__ wijT,
    const float* __restrict__ z, const float* __restrict__ eb1,
    float* __restrict__ Zc,
    const float* __restrict__ nw1, const float* __restrict__ nb1,
    const float* __restrict__ nw2, const float* __restrict__ nb2,
    ushort* __restrict__ h2b, int* __restrict__ ptab)
{
    __shared__ float smem[64 * 65];
    int b = blockIdx.x;
    int tid = threadIdx.x;

    if (b < PREP_B0) {
        int bb = b - TR3_B0;
        int k0 = (bb & 7) * 64;
        int n0 = (bb >> 3) * 64;
        int tx = tid & 63, ty = tid >> 6;
#pragma unroll
        for (int r = 0; r < 16; r++) {
            int row = r * 4 + ty;
            smem[row * 65 + tx] = nw3[(k0 + row) * NODE_OUT + n0 + tx];
        }
        __syncthreads();
#pragma unroll
        for (int c = 0; c < 16; c++) {
            int n = c * 4 + ty;
            nw3T[(size_t)(n0 + n) * HIDDEN + k0 + tx] = f2bf(smem[tx * 65 + n]);
        }
    } else if (b < ZC_B0) {
        int t = (b - PREP_B0) * 256 + tid;
        if (t < 256 * 512) {
            int n = t >> 9, k = t & 511;
            ew2T[t] = f2bf(ew2[k * 256 + n]);
        } else {
            int u = t - 256 * 512;
            int n = u >> 7, k = u & 127;
            float s = (n < 512) ? ew1[(256 + k) * 512 + n] : ew1[(384 + k) * 512 + (n - 512)];
            wijT[u] = f2bf(s);
        }
    } else if (b < ND_B0) {
        int b2 = b - ZC_B0;
        int r = b2 >> 1, o = (b2 & 1) * 256 + tid;
        float* zs = smem;
        zs[tid] = z[r * LATENT + tid];
        __syncthreads();
        float acc = 0.f;
#pragma unroll 8
        for (int k = 0; k < LATENT; k++) acc += zs[k] * ew1[k * HIDDEN + o];
        Zc[r * HIDDEN + o] = acc + eb1[o];
    } else if (b < PT_B0) {
        int b2 = b - ND_B0;
        int r = b2 >> 1, half = b2 & 1;
        float* zs = smem;
        float* hs = smem + 256;
        zs[tid] = z[r * LATENT + tid];
        __syncthreads();
        float a0 = 0.f, a1 = 0.f;
#pragma unroll 8
        for (int k = 0; k < LATENT; k++) {
            float zk = zs[k];
            a0 += zk * nw1[k * HIDDEN + tid];
            a1 += zk * nw1[k * HIDDEN + tid + 256];
        }
        hs[tid]       = fmaxf(a0 + nb1[tid], 0.f);
        hs[tid + 256] = fmaxf(a1 + nb1[tid + 256], 0.f);
        __syncthreads();
        int o = half * 256 + tid;
        float acc = 0.f;
#pragma unroll 8
        for (int k = 0; k < HIDDEN; k++) acc += hs[k] * nw2[k * HIDDEN + o];
        acc += nb2[o];
        h2b[r * HIDDEN + o] = f2bf(fmaxf(acc, 0.f));
    } else {
        int p = (b - PT_B0) * 256 + tid;
        if (p < NPAIRS) {
            int i = 0, off = 0;
            while (p - off >= MAX_NODES - 1 - i) { off += MAX_NODES - 1 - i; ++i; }
            int j = i + 1 + (p - off);
            ptab[p] = (i << 8) | j;
        }
    }
}

__global__ __launch_bounds__(256, 4) void k_node_out_mfma(
    const ushort* __restrict__ h2b, const ushort* __restrict__ nw3T,
    const float* __restrict__ nb3, float* __restrict__ node_probs,
    ushort* __restrict__ node_feats)
{
    int tid = threadIdx.x;
    int wave = tid >> 6, lane = tid & 63;
    int m16 = lane & 15, quad = lane >> 4;
    int n0 = (blockIdx.x >> 1) * 64;
    int m0 = (blockIdx.x & 1) * 64;
    int col = n0 + wave * 16 + m16;

    float4v acc[4];
#pragma unroll
    for (int mt = 0; mt < 4; mt++) acc[mt] = (float4v)(0.f);

    const ushort* bb = nw3T + (size_t)col * HIDDEN;
#pragma unroll
    for (int it = 0; it < 16; ++it) {
        int kk = it * 32 + quad * 8;
        short8 b = *(const short8*)(bb + kk);
#pragma unroll
        for (int mt = 0; mt < 4; mt++) {
            short8 a = *(const short8*)(h2b + (m0 + mt * 16 + m16) * HIDDEN + kk);
            acc[mt] = __builtin_amdgcn_mfma_f32_16x16x32_bf16(a, b, acc[mt], 0, 0, 0);
        }
    }
    float bias = nb3[col];
#pragma unroll
    for (int mt = 0; mt < 4; mt++)
#pragma unroll
        for (int t = 0; t < 4; t++) {
            int row = m0 + mt * 16 + quad * 4 + t;
            float v = acc[mt][t] + bias;
            node_probs[(size_t)row * NODE_OUT + col] = sigmoidf(v);
            node_feats[(size_t)row * NODE_OUT + col] = f2bf(v);
        }
}

__global__ __launch_bounds__(256, 4) void k_uv(
    const ushort* __restrict__ nf, const ushort* __restrict__ wijT,
    ushort* __restrict__ UV)
{
    int tid = threadIdx.x;
    int wave = tid >> 6, lane = tid & 63;
    int m16 = lane & 15, quad = lane >> 4;
    int bm = blockIdx.x >> 2, bn = blockIdx.x & 3;
    int base = bn * 256 + wave * 64;
    int r0 = bm * 64;

    float4v acc[4][4];
#pragma unroll
    for (int mt = 0; mt < 4; mt++)
#pragma unroll
        for (int nt = 0; nt < 4; nt++) acc[mt][nt] = (float4v)(0.f);

#pragma unroll
    for (int k0 = 0; k0 < NODE_F; k0 += 32) {
        int kk = k0 + quad * 8;
        short8 a0 = *(const short8*)(nf + (r0 + m16) * NODE_F + kk);
        short8 a1 = *(const short8*)(nf + (r0 + 16 + m16) * NODE_F + kk);
        short8 a2 = *(const short8*)(nf + (r0 + 32 + m16) * NODE_F + kk);
        short8 a3 = *(const short8*)(nf + (r0 + 48 + m16) * NODE_F + kk);
#pragma unroll
        for (int nt = 0; nt < 4; nt++) {
            int n = base + nt * 16 + m16;
            short8 b = *(const short8*)(wijT + n * NODE_F + kk);
            acc[0][nt] = __builtin_amdgcn_mfma_f32_16x16x32_bf16(a0, b, acc[0][nt], 0, 0, 0);
            acc[1][nt] = __builtin_amdgcn_mfma_f32_16x16x32_bf16(a1, b, acc[1][nt], 0, 0, 0);
            acc[2][nt] = __builtin_amdgcn_mfma_f32_16x16x32_bf16(a2, b, acc[2][nt], 0, 0, 0);
            acc[3][nt] = __builtin_amdgcn_mfma_f32_16x16x32_bf16(a3, b, acc[3][nt], 0, 0, 0);
        }
    }
#pragma unroll
    for (int nt = 0; nt < 4; nt++) {
        int colg = base + nt * 16 + m16;
#pragma unroll
        for (int mt = 0; mt < 4; mt++)
#pragma unroll
            for (int t = 0; t < 4; t++) {
                int rr = r0 + mt * 16 + quad * 4 + t;
                UV[(size_t)rr * 1024 + colg] = f2bf(acc[mt][nt][t]);
            }
    }
}

__global__ __launch_bounds__(512, 2) void k_edge8(
    const float* __restrict__ Zc, const ushort* __restrict__ UV,
    const ushort* __restrict__ ew2T, const float* __restrict__ ew3,
    const float* __restrict__ eb2, const float* __restrict__ eb3,
    const int* __restrict__ ptab, float* __restrict__ out_edges)
{
    __shared__ __align__(16) ushort h1[2][MTILE][HIDDEN + 8];
    __shared__ float part[MTILE][8];
    __shared__ int uo5[TPB][MTILE], vo5[TPB][MTILE];

    int tid  = threadIdx.x;
    int blk  = blockIdx.x;
    int b    = blk >> 1;
    int ti0  = (blk & 1) * TPB;

    if (tid < MTILE) {
#pragma unroll
        for (int t = 0; t < TPB; t++) {
            int p = (ti0 + t) * MTILE + tid;
            if (p >= NPAIRS) p = NPAIRS - 1;
            int ij = ptab[p];
            uo5[t][tid] = (b * MAX_NODES + (ij >> 8)) * 1024;
            vo5[t][tid] = (b * MAX_NODES + (ij & 255)) * 1024 + 512;
        }
    }

    int wave = tid >> 6, lane = tid & 63;
    int m16 = lane & 15, quad = lane >> 4;
    int c8 = lane * 8;
    int kk0 = quad * 8;

    float4v zA = *(const float4v*)(Zc + b * HIDDEN + c8);
    float4v zB = *(const float4v*)(Zc + b * HIDDEN + c8 + 4);

    const ushort* bb0 = ew2T + (wave * 32 + m16) * HIDDEN;
    const ushort* bb1 = ew2T + (wave * 32 + 16 + m16) * HIDDEN;
    short8 Breg[16][2];
#pragma unroll
    for (int kc = 0; kc < 16; kc++) {
        Breg[kc][0] = *(const short8*)(bb0 + kc * 32 + kk0);
        Breg[kc][1] = *(const short8*)(bb1 + kc * 32 + kk0);
    }
    float eb2v[2], ew3v[2];
    eb2v[0] = eb2[wave * 32 + m16];      eb2v[1] = eb2[wave * 32 + 16 + m16];
    ew3v[0] = ew3[wave * 32 + m16];      ew3v[1] = ew3[wave * 32 + 16 + m16];

    __syncthreads();

#pragma unroll
    for (int rr = 0; rr < 8; rr++) {
        int r = wave * 8 + rr;
        short8 u8 = *(const short8*)(UV + uo5[0][r] + c8);
        short8 v8 = *(const short8*)(UV + vo5[0][r] + c8);
        S8U hh;
#pragma unroll
        for (int e2 = 0; e2 < 4; e2++) {
            float z0 = (e2 < 2) ? zA[e2 * 2] : zB[e2 * 2 - 4];
            float z1 = (e2 < 2) ? zA[e2 * 2 + 1] : zB[e2 * 2 - 3];
            float f0 = fmaxf(z0 + bf2f((ushort)u8[e2 * 2]) + bf2f((ushort)v8[e2 * 2]), 0.f);
            float f1 = fmaxf(z1 + bf2f((ushort)u8[e2 * 2 + 1]) + bf2f((ushort)v8[e2 * 2 + 1]), 0.f);
            hh.u[e2] = pk_bf16(f0, f1);
        }
        *(short8*)&h1[0][r][c8] = hh.s;
    }
    __syncthreads();

    for (int t = 0; t < TPB; t++) {
        int cur = t & 1, nxt = cur ^ 1;
        bool hasNext = (t + 1 < TPB);

        float4v acc2[4][2];
#pragma unroll
        for (int mt = 0; mt < 4; mt++)
#pragma unroll
            for (int nt = 0; nt < 2; nt++) acc2[mt][nt] = (float4v)(0.f);

        short8 uu[4], vv[4];
        if (hasNext) {
#pragma unroll
            for (int rr = 0; rr < 4; rr++) {
                int r = wave * 8 + rr;
                uu[rr] = *(const short8*)(UV + uo5[t + 1][r] + c8);
                vv[rr] = *(const short8*)(UV + vo5[t + 1][r] + c8);
            }
        }
#pragma unroll
        for (int it = 0; it < 8; ++it) {
            int kk = it * 32 + kk0;
            short8 a0 = *(const short8*)&h1[cur][m16][kk];
            short8 a1 = *(const short8*)&h1[cur][16 + m16][kk];
            short8 a2 = *(const short8*)&h1[cur][32 + m16][kk];
            short8 a3 = *(const short8*)&h1[cur][48 + m16][kk];
            acc2[0][0] = __builtin_amdgcn_mfma_f32_16x16x32_bf16(a0, Breg[it][0], acc2[0][0], 0, 0, 0);
            acc2[1][0] = __builtin_amdgcn_mfma_f32_16x16x32_bf16(a1, Breg[it][0], acc2[1][0], 0, 0, 0);
            acc2[2][0] = __builtin_amdgcn_mfma_f32_16x16x32_bf16(a2, Breg[it][0], acc2[2][0], 0, 0, 0);
            acc2[3][0] = __builtin_amdgcn_mfma_f32_16x16x32_bf16(a3, Breg[it][0], acc2[3][0], 0, 0, 0);
            acc2[0][1] = __builtin_amdgcn_mfma_f32_16x16x32_bf16(a0, Breg[it][1], acc2[0][1], 0, 0, 0);
            acc2[1][1] = __builtin_amdgcn_mfma_f32_16x16x32_bf16(a1, Breg[it][1], acc2[1][1], 0, 0, 0);
            acc2[2][1] = __builtin_amdgcn_mfma_f32_16x16x32_bf16(a2, Breg[it][1], acc2[2][1], 0, 0, 0);
            acc2[3][1] = __builtin_amdgcn_mfma_f32_16x16x32_bf16(a3, Breg[it][1], acc2[3][1], 0, 0, 0);
        }
        if (hasNext) {
#pragma unroll
            for (int rr = 0; rr < 4; rr++) {
                int r = wave * 8 + rr;
                S8U hh;
#pragma unroll
                for (int e2 = 0; e2 < 4; e2++) {
                    float z0 = (e2 < 2) ? zA[e2 * 2] : zB[e2 * 2 - 4];
                    float z1 = (e2 < 2) ? zA[e2 * 2 + 1] : zB[e2 * 2 - 3];
                    float f0 = fmaxf(z0 + bf2f((ushort)uu[rr][e2 * 2]) + bf2f((ushort)vv[rr][e2 * 2]), 0.f);
                    float f1 = fmaxf(z1 + bf2f((ushort)uu[rr][e2 * 2 + 1]) + bf2f((ushort)vv[rr][e2 * 2 + 1]), 0.f);
                    hh.u[e2] = pk_bf16(f0, f1);
                }
                *(short8*)&h1[nxt][r][c8] = hh.s;
            }
#pragma unroll
            for (int rr = 0; rr < 4; rr++) {
                int r = wave * 8 + 4 + rr;
                uu[rr] = *(const short8*)(UV + uo5[t + 1][r] + c8);
                vv[rr] = *(const short8*)(UV + vo5[t + 1][r] + c8);
            }
        }
#pragma unroll
        for (int it = 8; it < 16; ++it) {
            int kk = it * 32 + kk0;
            short8 a0 = *(const short8*)&h1[cur][m16][kk];
            short8 a1 = *(const short8*)&h1[cur][16 + m16][kk];
            short8 a2 = *(const short8*)&h1[cur][32 + m16][kk];
            short8 a3 = *(const short8*)&h1[cur][48 + m16][kk];
            acc2[0][0] = __builtin_amdgcn_mfma_f32_16x16x32_bf16(a0, Breg[it][0], acc2[0][0], 0, 0, 0);
            acc2[1][0] = __builtin_amdgcn_mfma_f32_16x16x32_bf16(a1, Breg[it][0], acc2[1][0], 0, 0, 0);
            acc2[2][0] = __builtin_amdgcn_mfma_f32_16x16x32_bf16(a2, Breg[it][0], acc2[2][0], 0, 0, 0);
            acc2[3][0] = __builtin_amdgcn_mfma_f32_16x16x32_bf16(a3, Breg[it][0], acc2[3][0], 0, 0, 0);
            acc2[0][1] = __builtin_amdgcn_mfma_f32_16x16x32_bf16(a0, Breg[it][1], acc2[0][1], 0, 0, 0);
            acc2[1][1] = __builtin_amdgcn_mfma_f32_16x16x32_bf16(a1, Breg[it][1], acc2[1][1], 0, 0, 0);
            acc2[2][1] = __builtin_amdgcn_mfma_f32_16x16x32_bf16(a2, Breg[it][1], acc2[2][1], 0, 0, 0);
            acc2[3][1] = __builtin_amdgcn_mfma_f32_16x16x32_bf16(a3, Breg[it][1], acc2[3][1], 0, 0, 0);
        }
        if (hasNext) {
#pragma unroll
            for (int rr = 0; rr < 4; rr++) {
                int r = wave * 8 + 4 + rr;
                S8U hh;
#pragma unroll
                for (int e2 = 0; e2 < 4; e2++) {
                    float z0 = (e2 < 2) ? zA[e2 * 2] : zB[e2 * 2 - 4];
                    float z1 = (e2 < 2) ? zA[e2 * 2 + 1] : zB[e2 * 2 - 3];
                    float f0 = fmaxf(z0 + bf2f((ushort)uu[rr][e2 * 2]) + bf2f((ushort)vv[rr][e2 * 2]), 0.f);
                    float f1 = fmaxf(z1 + bf2f((ushort)uu[rr][e2 * 2 + 1]) + bf2f((ushort)vv[rr][e2 * 2 + 1]), 0.f);
                    hh.u[e2] = pk_bf16(f0, f1);
                }
                *(short8*)&h1[nxt][r][c8] = hh.s;
            }
        }

#pragma unroll
        for (int mt = 0; mt < 4; mt++)
#pragma unroll
            for (int tt = 0; tt < 4; tt++) {
                float s = 0.f;
#pragma unroll
                for (int nt = 0; nt < 2; nt++)
                    s += fmaxf(acc2[mt][nt][tt] + eb2v[nt], 0.f) * ew3v[nt];
                s += __shfl_xor(s, 1);
                s += __shfl_xor(s, 2);
                s += __shfl_xor(s, 4);
                s += __shfl_xor(s, 8);
                if (m16 == 0) part[mt * 16 + quad * 4 + tt][wave] = s;
            }
        __syncthreads();

        if (tid < MTILE) {
            int p = (ti0 + t) * MTILE + tid;
            if (p < NPAIRS) {
                float v = eb3[0];
#pragma unroll
                for (int w = 0; w < 8; w++) v += part[tid][w];
                out_edges[b * NPAIRS + p] = sigmoidf(v);
            }
        }
        __syncthreads();
    }
}

extern "C" void kernel_launch(void* const* d_in, const int* in_sizes, int n_in,
                              void* d_out, int out_size, void* d_ws, size_t ws_size,
                              hipStream_t stream) {
    const float* z   = (const float*)d_in[0];
    const float* nw1 = (const float*)d_in[1];
    const float* nb1 = (const float*)d_in[2];
    const float* nw2 = (const float*)d_in[3];
    const float* nb2 = (const float*)d_in[4];
    const float* nw3 = (const float*)d_in[5];
    const float* nb3 = (const float*)d_in[6];
    const float* ew1 = (const float*)d_in[7];
    const float* eb1 = (const float*)d_in[8];
    const float* ew2 = (const float*)d_in[9];
    const float* eb2 = (const float*)d_in[10];
    const float* ew3 = (const float*)d_in[11];
    const float* eb3 = (const float*)d_in[12];

    char* ws = (char*)d_ws;
    int*    ptab = (int*)(ws);                       // 1225*4
    ushort* h2b  = (ushort*)(ws + 262144);           // 131072
    ushort* nf   = (ushort*)(ws + 393216);           // 1638400
    ushort* ew2T = (ushort*)(ws + 2031616);          // 262144
    ushort* wijT = (ushort*)(ws + 2293760);          // 262144
    ushort* nw3T = (ushort*)(ws + 2555904);          // 6553600
    float*  Zc   = (float*)(ws + 9109504);           // 262144
    ushort* UV   = (ushort*)(ws + 9371648);          // 13107200

    float* out_nodes = (float*)d_out;                // 128*6400
    float* out_edges = out_nodes + BATCH * NODE_OUT; // 128*1225

    void* args[] = {
        (void*)&z, (void*)&nw1, (void*)&nb1, (void*)&nw2, (void*)&nb2,
        (void*)&nw3, (void*)&nb3, (void*)&ew1, (void*)&eb1, (void*)&ew2,
        (void*)&eb2, (void*)&ew3, (void*)&eb3,
        (void*)&ptab, (void*)&h2b, (void*)&nf, (void*)&ew2T, (void*)&wijT,
        (void*)&nw3T, (void*)&Zc, (void*)&UV, (void*)&out_nodes, (void*)&out_edges
    };
    hipError_t e = hipLaunchCooperativeKernel((void*)k_all, dim3(NBLK), dim3(NTHR),
                                              args, 0, stream);
    if (e != hipSuccess) {
        (void)hipGetLastError();   // clear, fall back to 4-launch path
        k_prep_all<<<PREPK_NB, 256, 0, stream>>>(nw3, nw3T, ew1, ew2, ew2T, wijT,
                                                 z, eb1, Zc, nw1, nb1, nw2, nb2,
                                                 h2b, ptab);
        k_node_out_mfma<<<200, 256, 0, stream>>>(h2b, nw3T, nb3, out_nodes, nf);
        k_uv<<<400, 256, 0, stream>>>(nf, wijT, UV);
        k_edge8<<<NBLK, 512, 0, stream>>>(Zc, UV, ew2T, ew3, eb2, eb3, ptab, out_edges);
    }
}

// Round 13
// 231.526 us; speedup vs baseline: 1.4372x; 1.4372x over previous
//
#include <hip/hip_runtime.h>
#include <hip/hip_bf16.h>
#include <math.h>

#define LATENT 256
#define HIDDEN 512
#define NODE_F 128
#define MAX_NODES 50
#define NPAIRS 1225        // 50*49/2
#define BATCH 128
#define NODE_OUT 6400      // MAX_NODES*NODE_F
#define MTILE 64           // edge rows per tile
#define TPB 10             // tiles per block (20 tiles/batch = 2 blocks/batch)
#define NBLK 256           // edge grid (1 block/CU)

typedef __attribute__((ext_vector_type(8))) short short8;
typedef __attribute__((ext_vector_type(4))) float float4v;

union S8U { short8 s; unsigned int u[4]; };

__device__ __forceinline__ float bf2f(ushort u) {
    union { unsigned int i; float f; } v; v.i = ((unsigned int)u) << 16; return v.f;
}
__device__ __forceinline__ ushort f2bf(float f) {
    union { unsigned int i; float f; } v; v.f = f;
    unsigned int r = v.i + 0x7fffu + ((v.i >> 16) & 1u);   // RNE
    return (ushort)(r >> 16);
}
__device__ __forceinline__ unsigned int pk_bf16(float f0, float f1) {
    __hip_bfloat162 p = __float22bfloat162_rn(float2{f0, f1});   // v_cvt_pk_bf16_f32 (RNE)
    unsigned int w; __builtin_memcpy(&w, &p, 4); return w;
}
__device__ __forceinline__ float sigmoidf(float x) {
    return 1.0f / (1.0f + __expf(-x));
}

// ================= fused prep kernel: 5 independent jobs, one launch =================
#define TR3_B0   0
#define PREP_B0  800
#define ZC_B0    1824
#define ND_B0    2080
#define PT_B0    2336
#define PREPK_NB 2341

__global__ __launch_bounds__(256) void k_prep_all(
    const float* __restrict__ nw3, ushort* __restrict__ nw3T,
    const float* __restrict__ ew1, const float* __restrict__ ew2,
    ushort* __restrict__ ew2T, ushort* __restrict__ wijT,
    const float* __restrict__ z, const float* __restrict__ eb1,
    float* __restrict__ Zc,
    const float* __restrict__ nw1, const float* __restrict__ nb1,
    const float* __restrict__ nw2, const float* __restrict__ nb2,
    ushort* __restrict__ h2b, int* __restrict__ ptab)
{
    __shared__ float smem[64 * 65];
    int b = blockIdx.x;
    int tid = threadIdx.x;

    if (b < PREP_B0) {
        // ---- nw3 transpose, 64x64 tiles (8 k-tiles x 100 n-tiles)
        int bb = b - TR3_B0;
        int k0 = (bb & 7) * 64;
        int n0 = (bb >> 3) * 64;
        int tx = tid & 63, ty = tid >> 6;   // 64 x 4
#pragma unroll
        for (int r = 0; r < 16; r++) {
            int row = r * 4 + ty;
            smem[row * 65 + tx] = nw3[(k0 + row) * NODE_OUT + n0 + tx];
        }
        __syncthreads();
#pragma unroll
        for (int c = 0; c < 16; c++) {
            int n = c * 4 + ty;
            nw3T[(size_t)(n0 + n) * HIDDEN + k0 + tx] = f2bf(smem[tx * 65 + n]);
        }
    } else if (b < ZC_B0) {
        int t = (b - PREP_B0) * 256 + tid;
        if (t < 256 * 512) {
            int n = t >> 9, k = t & 511;
            ew2T[t] = f2bf(ew2[k * 256 + n]);
        } else {
            int u = t - 256 * 512;          // < 1024*128
            int n = u >> 7, k = u & 127;
            float s = (n < 512) ? ew1[(256 + k) * 512 + n] : ew1[(384 + k) * 512 + (n - 512)];
            wijT[u] = f2bf(s);
        }
    } else if (b < ND_B0) {
        // ---- Zc = z @ W_z + eb1
        int b2 = b - ZC_B0;
        int r = b2 >> 1, o = (b2 & 1) * 256 + tid;
        float* zs = smem;
        zs[tid] = z[r * LATENT + tid];
        __syncthreads();
        float acc = 0.f;
#pragma unroll 8
        for (int k = 0; k < LATENT; k++) acc += zs[k] * ew1[k * HIDDEN + o];
        Zc[r * HIDDEN + o] = acc + eb1[o];
    } else if (b < PT_B0) {
        // ---- fused node MLP L1+L2
        int b2 = b - ND_B0;
        int r = b2 >> 1, half = b2 & 1;
        float* zs = smem;            // 256 floats
        float* hs = smem + 256;      // 512 floats
        zs[tid] = z[r * LATENT + tid];
        __syncthreads();
        float a0 = 0.f, a1 = 0.f;
#pragma unroll 8
        for (int k = 0; k < LATENT; k++) {
            float zk = zs[k];
            a0 += zk * nw1[k * HIDDEN + tid];
            a1 += zk * nw1[k * HIDDEN + tid + 256];
        }
        hs[tid]       = fmaxf(a0 + nb1[tid], 0.f);
        hs[tid + 256] = fmaxf(a1 + nb1[tid + 256], 0.f);
        __syncthreads();
        int o = half * 256 + tid;
        float acc = 0.f;
#pragma unroll 8
        for (int k = 0; k < HIDDEN; k++) acc += hs[k] * nw2[k * HIDDEN + o];
        acc += nb2[o];
        h2b[r * HIDDEN + o] = f2bf(fmaxf(acc, 0.f));
    } else {
        int p = (b - PT_B0) * 256 + tid;
        if (p < NPAIRS) {
            int i = 0, off = 0;
            while (p - off >= MAX_NODES - 1 - i) { off += MAX_NODES - 1 - i; ++i; }
            int j = i + 1 + (p - off);
            ptab[p] = (i << 8) | j;
        }
    }
}

// ---------------- merged node-L3 + UV kernel: grid 400 = 50 node-groups x 8 batch-16ths
// Phase A: logits[16 batches][128 feats of node g] via MFMA -> sigmoid->probs, bf16->LDS.
// Phase B: UV rows (batch, node g) = nf_row @ [W_i|W_j]  (16 x 1024, K=128).
__global__ __launch_bounds__(256, 2) void k_nodeuv(
    const ushort* __restrict__ h2b, const ushort* __restrict__ nw3T,
    const float* __restrict__ nb3, const ushort* __restrict__ wijT,
    float* __restrict__ node_probs, ushort* __restrict__ UV)
{
    __shared__ ushort nf_s[16][136];   // 4,352 B

    int tid = threadIdx.x;
    int wave = tid >> 6, lane = tid & 63;
    int m16 = lane & 15, quad = lane >> 4;
    int g  = blockIdx.x >> 3;    // node group 0..49
    int m0 = (blockIdx.x & 7) * 16;

    // ---- phase A: logits (16 x 128), wave covers 32 cols (nt=2)
    float4v accA[2];
    accA[0] = (float4v)(0.f); accA[1] = (float4v)(0.f);

    int colA0 = g * 128 + wave * 32 + m16;
    const ushort* a0p = h2b + (m0 + m16) * HIDDEN;
    const ushort* b0p = nw3T + (size_t)colA0 * HIDDEN;
    const ushort* b1p = nw3T + (size_t)(colA0 + 16) * HIDDEN;
#pragma unroll
    for (int it = 0; it < 16; ++it) {
        int kk = it * 32 + quad * 8;
        short8 a  = *(const short8*)(a0p + kk);
        short8 b0 = *(const short8*)(b0p + kk);
        short8 b1 = *(const short8*)(b1p + kk);
        accA[0] = __builtin_amdgcn_mfma_f32_16x16x32_bf16(a, b0, accA[0], 0, 0, 0);
        accA[1] = __builtin_amdgcn_mfma_f32_16x16x32_bf16(a, b1, accA[1], 0, 0, 0);
    }
#pragma unroll
    for (int nt = 0; nt < 2; nt++) {
        int col = colA0 + nt * 16;
        float bias = nb3[col];
#pragma unroll
        for (int t = 0; t < 4; t++) {
            int row = quad * 4 + t;   // 0..15
            float v = accA[nt][t] + bias;
            node_probs[(size_t)(m0 + row) * NODE_OUT + col] = sigmoidf(v);
            nf_s[row][wave * 32 + nt * 16 + m16] = f2bf(v);
        }
    }
    __syncthreads();

    // ---- phase B: UV rows (16 x 1024), K=128; wave covers 256 cols (nt=16)
    float4v accB[16];
#pragma unroll
    for (int nt = 0; nt < 16; nt++) accB[nt] = (float4v)(0.f);

    int base = wave * 256;
#pragma unroll
    for (int kit = 0; kit < 4; ++kit) {
        int kk = kit * 32 + quad * 8;
        short8 a = *(const short8*)&nf_s[m16][kk];
#pragma unroll
        for (int nt = 0; nt < 16; nt++) {
            int n = base + nt * 16 + m16;
            short8 b = *(const short8*)(wijT + n * NODE_F + kk);
            accB[nt] = __builtin_amdgcn_mfma_f32_16x16x32_bf16(a, b, accB[nt], 0, 0, 0);
        }
    }
#pragma unroll
    for (int nt = 0; nt < 16; nt++) {
        int colg = base + nt * 16 + m16;
#pragma unroll
        for (int t = 0; t < 4; t++) {
            int row = quad * 4 + t;
            UV[((size_t)(m0 + row) * MAX_NODES + g) * 1024 + colg] = f2bf(accB[nt][t]);
        }
    }
}

// ---------------- fused edge, persistent-B, TPB=10, grid 256 (1 block/CU) — R11 verbatim
__global__ __launch_bounds__(512, 2) void k_edge8(
    const float* __restrict__ Zc, const ushort* __restrict__ UV,
    const ushort* __restrict__ ew2T, const float* __restrict__ ew3,
    const float* __restrict__ eb2, const float* __restrict__ eb3,
    const int* __restrict__ ptab, float* __restrict__ out_edges)
{
    __shared__ __align__(16) ushort h1[2][MTILE][HIDDEN + 8]; // 133,120 B
    __shared__ float part[MTILE][8];
    __shared__ int uo5[TPB][MTILE], vo5[TPB][MTILE];

    int tid  = threadIdx.x;
    int blk  = blockIdx.x;
    int b    = blk >> 1;
    int ti0  = (blk & 1) * TPB;

    if (tid < MTILE) {
#pragma unroll
        for (int t = 0; t < TPB; t++) {
            int p = (ti0 + t) * MTILE + tid;
            if (p >= NPAIRS) p = NPAIRS - 1;
            int ij = ptab[p];
            uo5[t][tid] = (b * MAX_NODES + (ij >> 8)) * 1024;
            vo5[t][tid] = (b * MAX_NODES + (ij & 255)) * 1024 + 512;
        }
    }

    int wave = tid >> 6, lane = tid & 63;
    int m16 = lane & 15, quad = lane >> 4;
    int c8 = lane * 8;
    int kk0 = quad * 8;

    float4v zA = *(const float4v*)(Zc + b * HIDDEN + c8);
    float4v zB = *(const float4v*)(Zc + b * HIDDEN + c8 + 4);

    const ushort* bb0 = ew2T + (wave * 32 + m16) * HIDDEN;
    const ushort* bb1 = ew2T + (wave * 32 + 16 + m16) * HIDDEN;
    short8 Breg[16][2];
#pragma unroll
    for (int kc = 0; kc < 16; kc++) {
        Breg[kc][0] = *(const short8*)(bb0 + kc * 32 + kk0);
        Breg[kc][1] = *(const short8*)(bb1 + kc * 32 + kk0);
    }
    float eb2v[2], ew3v[2];
    eb2v[0] = eb2[wave * 32 + m16];      eb2v[1] = eb2[wave * 32 + 16 + m16];
    ew3v[0] = ew3[wave * 32 + m16];      ew3v[1] = ew3[wave * 32 + 16 + m16];

    __syncthreads();

#pragma unroll
    for (int rr = 0; rr < 8; rr++) {
        int r = wave * 8 + rr;
        short8 u8 = *(const short8*)(UV + uo5[0][r] + c8);
        short8 v8 = *(const short8*)(UV + vo5[0][r] + c8);
        S8U hh;
#pragma unroll
        for (int e2 = 0; e2 < 4; e2++) {
            float z0 = (e2 < 2) ? zA[e2 * 2] : zB[e2 * 2 - 4];
            float z1 = (e2 < 2) ? zA[e2 * 2 + 1] : zB[e2 * 2 - 3];
            float f0 = fmaxf(z0 + bf2f((ushort)u8[e2 * 2]) + bf2f((ushort)v8[e2 * 2]), 0.f);
            float f1 = fmaxf(z1 + bf2f((ushort)u8[e2 * 2 + 1]) + bf2f((ushort)v8[e2 * 2 + 1]), 0.f);
            hh.u[e2] = pk_bf16(f0, f1);
        }
        *(short8*)&h1[0][r][c8] = hh.s;
    }
    __syncthreads();

    for (int t = 0; t < TPB; t++) {
        int cur = t & 1, nxt = cur ^ 1;
        bool hasNext = (t + 1 < TPB);

        float4v acc2[4][2];
#pragma unroll
        for (int mt = 0; mt < 4; mt++)
#pragma unroll
            for (int nt = 0; nt < 2; nt++) acc2[mt][nt] = (float4v)(0.f);

        short8 uu[4], vv[4];
        if (hasNext) {
#pragma unroll
            for (int rr = 0; rr < 4; rr++) {
                int r = wave * 8 + rr;
                uu[rr] = *(const short8*)(UV + uo5[t + 1][r] + c8);
                vv[rr] = *(const short8*)(UV + vo5[t + 1][r] + c8);
            }
        }
#pragma unroll
        for (int it = 0; it < 8; ++it) {
            int kk = it * 32 + kk0;
            short8 a0 = *(const short8*)&h1[cur][m16][kk];
            short8 a1 = *(const short8*)&h1[cur][16 + m16][kk];
            short8 a2 = *(const short8*)&h1[cur][32 + m16][kk];
            short8 a3 = *(const short8*)&h1[cur][48 + m16][kk];
            acc2[0][0] = __builtin_amdgcn_mfma_f32_16x16x32_bf16(a0, Breg[it][0], acc2[0][0], 0, 0, 0);
            acc2[1][0] = __builtin_amdgcn_mfma_f32_16x16x32_bf16(a1, Breg[it][0], acc2[1][0], 0, 0, 0);
            acc2[2][0] = __builtin_amdgcn_mfma_f32_16x16x32_bf16(a2, Breg[it][0], acc2[2][0], 0, 0, 0);
            acc2[3][0] = __builtin_amdgcn_mfma_f32_16x16x32_bf16(a3, Breg[it][0], acc2[3][0], 0, 0, 0);
            acc2[0][1] = __builtin_amdgcn_mfma_f32_16x16x32_bf16(a0, Breg[it][1], acc2[0][1], 0, 0, 0);
            acc2[1][1] = __builtin_amdgcn_mfma_f32_16x16x32_bf16(a1, Breg[it][1], acc2[1][1], 0, 0, 0);
            acc2[2][1] = __builtin_amdgcn_mfma_f32_16x16x32_bf16(a2, Breg[it][1], acc2[2][1], 0, 0, 0);
            acc2[3][1] = __builtin_amdgcn_mfma_f32_16x16x32_bf16(a3, Breg[it][1], acc2[3][1], 0, 0, 0);
        }
        if (hasNext) {
#pragma unroll
            for (int rr = 0; rr < 4; rr++) {
                int r = wave * 8 + rr;
                S8U hh;
#pragma unroll
                for (int e2 = 0; e2 < 4; e2++) {
                    float z0 = (e2 < 2) ? zA[e2 * 2] : zB[e2 * 2 - 4];
                    float z1 = (e2 < 2) ? zA[e2 * 2 + 1] : zB[e2 * 2 - 3];
                    float f0 = fmaxf(z0 + bf2f((ushort)uu[rr][e2 * 2]) + bf2f((ushort)vv[rr][e2 * 2]), 0.f);
                    float f1 = fmaxf(z1 + bf2f((ushort)uu[rr][e2 * 2 + 1]) + bf2f((ushort)vv[rr][e2 * 2 + 1]), 0.f);
                    hh.u[e2] = pk_bf16(f0, f1);
                }
                *(short8*)&h1[nxt][r][c8] = hh.s;
            }
#pragma unroll
            for (int rr = 0; rr < 4; rr++) {
                int r = wave * 8 + 4 + rr;
                uu[rr] = *(const short8*)(UV + uo5[t + 1][r] + c8);
                vv[rr] = *(const short8*)(UV + vo5[t + 1][r] + c8);
            }
        }
#pragma unroll
        for (int it = 8; it < 16; ++it) {
            int kk = it * 32 + kk0;
            short8 a0 = *(const short8*)&h1[cur][m16][kk];
            short8 a1 = *(const short8*)&h1[cur][16 + m16][kk];
            short8 a2 = *(const short8*)&h1[cur][32 + m16][kk];
            short8 a3 = *(const short8*)&h1[cur][48 + m16][kk];
            acc2[0][0] = __builtin_amdgcn_mfma_f32_16x16x32_bf16(a0, Breg[it][0], acc2[0][0], 0, 0, 0);
            acc2[1][0] = __builtin_amdgcn_mfma_f32_16x16x32_bf16(a1, Breg[it][0], acc2[1][0], 0, 0, 0);
            acc2[2][0] = __builtin_amdgcn_mfma_f32_16x16x32_bf16(a2, Breg[it][0], acc2[2][0], 0, 0, 0);
            acc2[3][0] = __builtin_amdgcn_mfma_f32_16x16x32_bf16(a3, Breg[it][0], acc2[3][0], 0, 0, 0);
            acc2[0][1] = __builtin_amdgcn_mfma_f32_16x16x32_bf16(a0, Breg[it][1], acc2[0][1], 0, 0, 0);
            acc2[1][1] = __builtin_amdgcn_mfma_f32_16x16x32_bf16(a1, Breg[it][1], acc2[1][1], 0, 0, 0);
            acc2[2][1] = __builtin_amdgcn_mfma_f32_16x16x32_bf16(a2, Breg[it][1], acc2[2][1], 0, 0, 0);
            acc2[3][1] = __builtin_amdgcn_mfma_f32_16x16x32_bf16(a3, Breg[it][1], acc2[3][1], 0, 0, 0);
        }
        if (hasNext) {
#pragma unroll
            for (int rr = 0; rr < 4; rr++) {
                int r = wave * 8 + 4 + rr;
                S8U hh;
#pragma unroll
                for (int e2 = 0; e2 < 4; e2++) {
                    float z0 = (e2 < 2) ? zA[e2 * 2] : zB[e2 * 2 - 4];
                    float z1 = (e2 < 2) ? zA[e2 * 2 + 1] : zB[e2 * 2 - 3];
                    float f0 = fmaxf(z0 + bf2f((ushort)uu[rr][e2 * 2]) + bf2f((ushort)vv[rr][e2 * 2]), 0.f);
                    float f1 = fmaxf(z1 + bf2f((ushort)uu[rr][e2 * 2 + 1]) + bf2f((ushort)vv[rr][e2 * 2 + 1]), 0.f);
                    hh.u[e2] = pk_bf16(f0, f1);
                }
                *(short8*)&h1[nxt][r][c8] = hh.s;
            }
        }

#pragma unroll
        for (int mt = 0; mt < 4; mt++)
#pragma unroll
            for (int tt = 0; tt < 4; tt++) {
                float s = 0.f;
#pragma unroll
                for (int nt = 0; nt < 2; nt++)
                    s += fmaxf(acc2[mt][nt][tt] + eb2v[nt], 0.f) * ew3v[nt];
                s += __shfl_xor(s, 1);
                s += __shfl_xor(s, 2);
                s += __shfl_xor(s, 4);
                s += __shfl_xor(s, 8);
                if (m16 == 0) part[mt * 16 + quad * 4 + tt][wave] = s;
            }
        __syncthreads();

        if (tid < MTILE) {
            int p = (ti0 + t) * MTILE + tid;
            if (p < NPAIRS) {
                float v = eb3[0];
#pragma unroll
                for (int w = 0; w < 8; w++) v += part[tid][w];
                out_edges[b * NPAIRS + p] = sigmoidf(v);
            }
        }
        __syncthreads();
    }
}

extern "C" void kernel_launch(void* const* d_in, const int* in_sizes, int n_in,
                              void* d_out, int out_size, void* d_ws, size_t ws_size,
                              hipStream_t stream) {
    const float* z   = (const float*)d_in[0];
    const float* nw1 = (const float*)d_in[1];
    const float* nb1 = (const float*)d_in[2];
    const float* nw2 = (const float*)d_in[3];
    const float* nb2 = (const float*)d_in[4];
    const float* nw3 = (const float*)d_in[5];
    const float* nb3 = (const float*)d_in[6];
    const float* ew1 = (const float*)d_in[7];
    const float* eb1 = (const float*)d_in[8];
    const float* ew2 = (const float*)d_in[9];
    const float* eb2 = (const float*)d_in[10];
    const float* ew3 = (const float*)d_in[11];
    const float* eb3 = (const float*)d_in[12];

    char* ws = (char*)d_ws;
    int*    ptab = (int*)(ws);                       // 1225*4
    ushort* h2b  = (ushort*)(ws + 262144);           // 131072
    ushort* ew2T = (ushort*)(ws + 2031616);          // 262144
    ushort* wijT = (ushort*)(ws + 2293760);          // 262144
    ushort* nw3T = (ushort*)(ws + 2555904);          // 6553600
    float*  Zc   = (float*)(ws + 9109504);           // 262144
    ushort* UV   = (ushort*)(ws + 9371648);          // 13107200

    float* out_nodes = (float*)d_out;                // 128*6400
    float* out_edges = out_nodes + BATCH * NODE_OUT; // 128*1225

    k_prep_all<<<PREPK_NB, 256, 0, stream>>>(nw3, nw3T, ew1, ew2, ew2T, wijT,
                                             z, eb1, Zc, nw1, nb1, nw2, nb2,
                                             h2b, ptab);
    k_nodeuv<<<400, 256, 0, stream>>>(h2b, nw3T, nb3, wijT, out_nodes, UV);
    k_edge8<<<NBLK, 512, 0, stream>>>(Zc, UV, ew2T, ew3, eb2, eb3, ptab, out_edges);
}

// Round 14
// 221.929 us; speedup vs baseline: 1.4993x; 1.0432x over previous
//
#include <hip/hip_runtime.h>
#include <hip/hip_bf16.h>
#include <math.h>

#define LATENT 256
#define HIDDEN 512
#define NODE_F 128
#define MAX_NODES 50
#define NPAIRS 1225        // 50*49/2
#define BATCH 128
#define NODE_OUT 6400      // MAX_NODES*NODE_F
#define MTILE 64           // edge rows per tile
#define TPB 10             // tiles per block (20 tiles/batch = 2 blocks/batch)
#define NBLK 256           // edge grid (1 block/CU)

typedef __attribute__((ext_vector_type(8))) short short8;
typedef __attribute__((ext_vector_type(4))) float float4v;

union S8U { short8 s; unsigned int u[4]; };

__device__ __forceinline__ float bf2f(ushort u) {
    union { unsigned int i; float f; } v; v.i = ((unsigned int)u) << 16; return v.f;
}
__device__ __forceinline__ ushort f2bf(float f) {
    union { unsigned int i; float f; } v; v.f = f;
    unsigned int r = v.i + 0x7fffu + ((v.i >> 16) & 1u);   // RNE
    return (ushort)(r >> 16);
}
__device__ __forceinline__ unsigned int pk_bf16(float f0, float f1) {
    __hip_bfloat162 p = __float22bfloat162_rn(float2{f0, f1});   // v_cvt_pk_bf16_f32 (RNE)
    unsigned int w; __builtin_memcpy(&w, &p, 4); return w;
}
__device__ __forceinline__ float sigmoidf(float x) {
    return 1.0f / (1.0f + __expf(-x));
}

// ================= fused prep kernel =================
// [0,800)      nw3T 64x64-tile transpose
// [800,832)    ew2T 64x64-tile transpose (8 k-tiles x 4 n-tiles)
// [832,848)    wijT U-half tiles (2 k x 8 n)
// [848,864)    wijT V-half tiles (2 k x 8 n)
// [864,1120)   Zc = z @ W_z + eb1
// [1120,1376)  fused node MLP L1+L2 -> h2b
// [1376,1381)  ptab
#define TR3_B0   0
#define EW2_B0   800
#define WIU_B0   832
#define WIV_B0   848
#define ZC_B0    864
#define ND_B0    1120
#define PT_B0    1376
#define PREPK_NB 1381

__global__ __launch_bounds__(256) void k_prep_all(
    const float* __restrict__ nw3, ushort* __restrict__ nw3T,
    const float* __restrict__ ew1, const float* __restrict__ ew2,
    ushort* __restrict__ ew2T, ushort* __restrict__ wijT,
    const float* __restrict__ z, const float* __restrict__ eb1,
    float* __restrict__ Zc,
    const float* __restrict__ nw1, const float* __restrict__ nb1,
    const float* __restrict__ nw2, const float* __restrict__ nb2,
    ushort* __restrict__ h2b, int* __restrict__ ptab)
{
    __shared__ float smem[64 * 65];
    int b = blockIdx.x;
    int tid = threadIdx.x;
    int tx = tid & 63, ty = tid >> 6;   // 64 x 4

    if (b < EW2_B0) {
        // ---- nw3 transpose, 64x64 tiles (8 k-tiles x 100 n-tiles)
        int bb = b - TR3_B0;
        int k0 = (bb & 7) * 64;
        int n0 = (bb >> 3) * 64;
#pragma unroll
        for (int r = 0; r < 16; r++) {
            int row = r * 4 + ty;
            smem[row * 65 + tx] = nw3[(k0 + row) * NODE_OUT + n0 + tx];
        }
        __syncthreads();
#pragma unroll
        for (int c = 0; c < 16; c++) {
            int n = c * 4 + ty;
            nw3T[(size_t)(n0 + n) * HIDDEN + k0 + tx] = f2bf(smem[tx * 65 + n]);
        }
    } else if (b < WIU_B0) {
        // ---- ew2T[n][k] = ew2[k][n], tiled: ew2 is 512x256
        int bb = b - EW2_B0;
        int k0 = (bb >> 2) * 64;
        int n0 = (bb & 3) * 64;
#pragma unroll
        for (int r = 0; r < 16; r++) {
            int row = r * 4 + ty;
            smem[row * 65 + tx] = ew2[(k0 + row) * 256 + n0 + tx];
        }
        __syncthreads();
#pragma unroll
        for (int c = 0; c < 16; c++) {
            int n = c * 4 + ty;
            ew2T[(n0 + n) * HIDDEN + k0 + tx] = f2bf(smem[tx * 65 + n]);
        }
    } else if (b < WIV_B0) {
        // ---- wijT U-half: wijT[n][k] = ew1[256+k][n], n<512, k<128
        int bb = b - WIU_B0;
        int k0 = (bb >> 3) * 64;
        int n0 = (bb & 7) * 64;
#pragma unroll
        for (int r = 0; r < 16; r++) {
            int row = r * 4 + ty;
            smem[row * 65 + tx] = ew1[(256 + k0 + row) * 512 + n0 + tx];
        }
        __syncthreads();
#pragma unroll
        for (int c = 0; c < 16; c++) {
            int n = c * 4 + ty;
            wijT[(n0 + n) * NODE_F + k0 + tx] = f2bf(smem[tx * 65 + n]);
        }
    } else if (b < ZC_B0) {
        // ---- wijT V-half: wijT[512+n][k] = ew1[384+k][n], n<512, k<128
        int bb = b - WIV_B0;
        int k0 = (bb >> 3) * 64;
        int n0 = (bb & 7) * 64;
#pragma unroll
        for (int r = 0; r < 16; r++) {
            int row = r * 4 + ty;
            smem[row * 65 + tx] = ew1[(384 + k0 + row) * 512 + n0 + tx];
        }
        __syncthreads();
#pragma unroll
        for (int c = 0; c < 16; c++) {
            int n = c * 4 + ty;
            wijT[(512 + n0 + n) * NODE_F + k0 + tx] = f2bf(smem[tx * 65 + n]);
        }
    } else if (b < ND_B0) {
        // ---- Zc = z @ W_z + eb1
        int b2 = b - ZC_B0;
        int r = b2 >> 1, o = (b2 & 1) * 256 + tid;
        float* zs = smem;
        zs[tid] = z[r * LATENT + tid];
        __syncthreads();
        float acc = 0.f;
#pragma unroll 8
        for (int k = 0; k < LATENT; k++) acc += zs[k] * ew1[k * HIDDEN + o];
        Zc[r * HIDDEN + o] = acc + eb1[o];
    } else if (b < PT_B0) {
        // ---- fused node MLP L1+L2
        int b2 = b - ND_B0;
        int r = b2 >> 1, half = b2 & 1;
        float* zs = smem;            // 256 floats
        float* hs = smem + 256;      // 512 floats
        zs[tid] = z[r * LATENT + tid];
        __syncthreads();
        float a0 = 0.f, a1 = 0.f;
#pragma unroll 8
        for (int k = 0; k < LATENT; k++) {
            float zk = zs[k];
            a0 += zk * nw1[k * HIDDEN + tid];
            a1 += zk * nw1[k * HIDDEN + tid + 256];
        }
        hs[tid]       = fmaxf(a0 + nb1[tid], 0.f);
        hs[tid + 256] = fmaxf(a1 + nb1[tid + 256], 0.f);
        __syncthreads();
        int o = half * 256 + tid;
        float acc = 0.f;
#pragma unroll 8
        for (int k = 0; k < HIDDEN; k++) acc += hs[k] * nw2[k * HIDDEN + o];
        acc += nb2[o];
        h2b[r * HIDDEN + o] = f2bf(fmaxf(acc, 0.f));
    } else {
        int p = (b - PT_B0) * 256 + tid;
        if (p < NPAIRS) {
            int i = 0, off = 0;
            while (p - off >= MAX_NODES - 1 - i) { off += MAX_NODES - 1 - i; ++i; }
            int j = i + 1 + (p - off);
            ptab[p] = (i << 8) | j;
        }
    }
}

// ---------------- node layer 3 via MFMA: grid 200 = 100 n-tiles(64) x 2 m-halves(64)
__global__ __launch_bounds__(256, 4) void k_node_out_mfma(
    const ushort* __restrict__ h2b, const ushort* __restrict__ nw3T,
    const float* __restrict__ nb3, float* __restrict__ node_probs,
    ushort* __restrict__ node_feats)
{
    int tid = threadIdx.x;
    int wave = tid >> 6, lane = tid & 63;
    int m16 = lane & 15, quad = lane >> 4;
    int n0 = (blockIdx.x >> 1) * 64;
    int m0 = (blockIdx.x & 1) * 64;
    int col = n0 + wave * 16 + m16;

    float4v acc[4];
#pragma unroll
    for (int mt = 0; mt < 4; mt++) acc[mt] = (float4v)(0.f);

    const ushort* bb = nw3T + (size_t)col * HIDDEN;
#pragma unroll
    for (int it = 0; it < 16; ++it) {
        int kk = it * 32 + quad * 8;
        short8 b = *(const short8*)(bb + kk);
#pragma unroll
        for (int mt = 0; mt < 4; mt++) {
            short8 a = *(const short8*)(h2b + (m0 + mt * 16 + m16) * HIDDEN + kk);
            acc[mt] = __builtin_amdgcn_mfma_f32_16x16x32_bf16(a, b, acc[mt], 0, 0, 0);
        }
    }
    float bias = nb3[col];
#pragma unroll
    for (int mt = 0; mt < 4; mt++)
#pragma unroll
        for (int t = 0; t < 4; t++) {
            int row = m0 + mt * 16 + quad * 4 + t;
            float v = acc[mt][t] + bias;
            node_probs[(size_t)row * NODE_OUT + col] = sigmoidf(v);
            node_feats[(size_t)row * NODE_OUT + col] = f2bf(v);
        }
}

// ---------------- UV = node_feats @ [W_i|W_j]   (6400 x 1024, bf16 out)
__global__ __launch_bounds__(256, 4) void k_uv(
    const ushort* __restrict__ nf, const ushort* __restrict__ wijT,
    ushort* __restrict__ UV)
{
    int tid = threadIdx.x;
    int wave = tid >> 6, lane = tid & 63;
    int m16 = lane & 15, quad = lane >> 4;
    int bm = blockIdx.x >> 2, bn = blockIdx.x & 3;
    int base = bn * 256 + wave * 64;
    int r0 = bm * 64;

    float4v acc[4][4];
#pragma unroll
    for (int mt = 0; mt < 4; mt++)
#pragma unroll
        for (int nt = 0; nt < 4; nt++) acc[mt][nt] = (float4v)(0.f);

#pragma unroll
    for (int k0 = 0; k0 < NODE_F; k0 += 32) {
        int kk = k0 + quad * 8;
        short8 a0 = *(const short8*)(nf + (r0 + m16) * NODE_F + kk);
        short8 a1 = *(const short8*)(nf + (r0 + 16 + m16) * NODE_F + kk);
        short8 a2 = *(const short8*)(nf + (r0 + 32 + m16) * NODE_F + kk);
        short8 a3 = *(const short8*)(nf + (r0 + 48 + m16) * NODE_F + kk);
#pragma unroll
        for (int nt = 0; nt < 4; nt++) {
            int n = base + nt * 16 + m16;
            short8 b = *(const short8*)(wijT + n * NODE_F + kk);
            acc[0][nt] = __builtin_amdgcn_mfma_f32_16x16x32_bf16(a0, b, acc[0][nt], 0, 0, 0);
            acc[1][nt] = __builtin_amdgcn_mfma_f32_16x16x32_bf16(a1, b, acc[1][nt], 0, 0, 0);
            acc[2][nt] = __builtin_amdgcn_mfma_f32_16x16x32_bf16(a2, b, acc[2][nt], 0, 0, 0);
            acc[3][nt] = __builtin_amdgcn_mfma_f32_16x16x32_bf16(a3, b, acc[3][nt], 0, 0, 0);
        }
    }
#pragma unroll
    for (int nt = 0; nt < 4; nt++) {
        int colg = base + nt * 16 + m16;
#pragma unroll
        for (int mt = 0; mt < 4; mt++)
#pragma unroll
            for (int t = 0; t < 4; t++) {
                int rr = r0 + mt * 16 + quad * 4 + t;
                UV[(size_t)rr * 1024 + colg] = f2bf(acc[mt][nt][t]);
            }
    }
}

// ---------------- fused edge, persistent-B, TPB=10, grid 256 (1 block/CU) — R11 verbatim
__global__ __launch_bounds__(512, 2) void k_edge8(
    const float* __restrict__ Zc, const ushort* __restrict__ UV,
    const ushort* __restrict__ ew2T, const float* __restrict__ ew3,
    const float* __restrict__ eb2, const float* __restrict__ eb3,
    const int* __restrict__ ptab, float* __restrict__ out_edges)
{
    __shared__ __align__(16) ushort h1[2][MTILE][HIDDEN + 8]; // 133,120 B
    __shared__ float part[MTILE][8];
    __shared__ int uo5[TPB][MTILE], vo5[TPB][MTILE];

    int tid  = threadIdx.x;
    int blk  = blockIdx.x;
    int b    = blk >> 1;
    int ti0  = (blk & 1) * TPB;

    if (tid < MTILE) {
#pragma unroll
        for (int t = 0; t < TPB; t++) {
            int p = (ti0 + t) * MTILE + tid;
            if (p >= NPAIRS) p = NPAIRS - 1;
            int ij = ptab[p];
            uo5[t][tid] = (b * MAX_NODES + (ij >> 8)) * 1024;
            vo5[t][tid] = (b * MAX_NODES + (ij & 255)) * 1024 + 512;
        }
    }

    int wave = tid >> 6, lane = tid & 63;
    int m16 = lane & 15, quad = lane >> 4;
    int c8 = lane * 8;
    int kk0 = quad * 8;

    float4v zA = *(const float4v*)(Zc + b * HIDDEN + c8);
    float4v zB = *(const float4v*)(Zc + b * HIDDEN + c8 + 4);

    const ushort* bb0 = ew2T + (wave * 32 + m16) * HIDDEN;
    const ushort* bb1 = ew2T + (wave * 32 + 16 + m16) * HIDDEN;
    short8 Breg[16][2];
#pragma unroll
    for (int kc = 0; kc < 16; kc++) {
        Breg[kc][0] = *(const short8*)(bb0 + kc * 32 + kk0);
        Breg[kc][1] = *(const short8*)(bb1 + kc * 32 + kk0);
    }
    float eb2v[2], ew3v[2];
    eb2v[0] = eb2[wave * 32 + m16];      eb2v[1] = eb2[wave * 32 + 16 + m16];
    ew3v[0] = ew3[wave * 32 + m16];      ew3v[1] = ew3[wave * 32 + 16 + m16];

    __syncthreads();

#pragma unroll
    for (int rr = 0; rr < 8; rr++) {
        int r = wave * 8 + rr;
        short8 u8 = *(const short8*)(UV + uo5[0][r] + c8);
        short8 v8 = *(const short8*)(UV + vo5[0][r] + c8);
        S8U hh;
#pragma unroll
        for (int e2 = 0; e2 < 4; e2++) {
            float z0 = (e2 < 2) ? zA[e2 * 2] : zB[e2 * 2 - 4];
            float z1 = (e2 < 2) ? zA[e2 * 2 + 1] : zB[e2 * 2 - 3];
            float f0 = fmaxf(z0 + bf2f((ushort)u8[e2 * 2]) + bf2f((ushort)v8[e2 * 2]), 0.f);
            float f1 = fmaxf(z1 + bf2f((ushort)u8[e2 * 2 + 1]) + bf2f((ushort)v8[e2 * 2 + 1]), 0.f);
            hh.u[e2] = pk_bf16(f0, f1);
        }
        *(short8*)&h1[0][r][c8] = hh.s;
    }
    __syncthreads();

    for (int t = 0; t < TPB; t++) {
        int cur = t & 1, nxt = cur ^ 1;
        bool hasNext = (t + 1 < TPB);

        float4v acc2[4][2];
#pragma unroll
        for (int mt = 0; mt < 4; mt++)
#pragma unroll
            for (int nt = 0; nt < 2; nt++) acc2[mt][nt] = (float4v)(0.f);

        short8 uu[4], vv[4];
        if (hasNext) {
#pragma unroll
            for (int rr = 0; rr < 4; rr++) {
                int r = wave * 8 + rr;
                uu[rr] = *(const short8*)(UV + uo5[t + 1][r] + c8);
                vv[rr] = *(const short8*)(UV + vo5[t + 1][r] + c8);
            }
        }
#pragma unroll
        for (int it = 0; it < 8; ++it) {
            int kk = it * 32 + kk0;
            short8 a0 = *(const short8*)&h1[cur][m16][kk];
            short8 a1 = *(const short8*)&h1[cur][16 + m16][kk];
            short8 a2 = *(const short8*)&h1[cur][32 + m16][kk];
            short8 a3 = *(const short8*)&h1[cur][48 + m16][kk];
            acc2[0][0] = __builtin_amdgcn_mfma_f32_16x16x32_bf16(a0, Breg[it][0], acc2[0][0], 0, 0, 0);
            acc2[1][0] = __builtin_amdgcn_mfma_f32_16x16x32_bf16(a1, Breg[it][0], acc2[1][0], 0, 0, 0);
            acc2[2][0] = __builtin_amdgcn_mfma_f32_16x16x32_bf16(a2, Breg[it][0], acc2[2][0], 0, 0, 0);
            acc2[3][0] = __builtin_amdgcn_mfma_f32_16x16x32_bf16(a3, Breg[it][0], acc2[3][0], 0, 0, 0);
            acc2[0][1] = __builtin_amdgcn_mfma_f32_16x16x32_bf16(a0, Breg[it][1], acc2[0][1], 0, 0, 0);
            acc2[1][1] = __builtin_amdgcn_mfma_f32_16x16x32_bf16(a1, Breg[it][1], acc2[1][1], 0, 0, 0);
            acc2[2][1] = __builtin_amdgcn_mfma_f32_16x16x32_bf16(a2, Breg[it][1], acc2[2][1], 0, 0, 0);
            acc2[3][1] = __builtin_amdgcn_mfma_f32_16x16x32_bf16(a3, Breg[it][1], acc2[3][1], 0, 0, 0);
        }
        if (hasNext) {
#pragma unroll
            for (int rr = 0; rr < 4; rr++) {
                int r = wave * 8 + rr;
                S8U hh;
#pragma unroll
                for (int e2 = 0; e2 < 4; e2++) {
                    float z0 = (e2 < 2) ? zA[e2 * 2] : zB[e2 * 2 - 4];
                    float z1 = (e2 < 2) ? zA[e2 * 2 + 1] : zB[e2 * 2 - 3];
                    float f0 = fmaxf(z0 + bf2f((ushort)uu[rr][e2 * 2]) + bf2f((ushort)vv[rr][e2 * 2]), 0.f);
                    float f1 = fmaxf(z1 + bf2f((ushort)uu[rr][e2 * 2 + 1]) + bf2f((ushort)vv[rr][e2 * 2 + 1]), 0.f);
                    hh.u[e2] = pk_bf16(f0, f1);
                }
                *(short8*)&h1[nxt][r][c8] = hh.s;
            }
#pragma unroll
            for (int rr = 0; rr < 4; rr++) {
                int r = wave * 8 + 4 + rr;
                uu[rr] = *(const short8*)(UV + uo5[t + 1][r] + c8);
                vv[rr] = *(const short8*)(UV + vo5[t + 1][r] + c8);
            }
        }
#pragma unroll
        for (int it = 8; it < 16; ++it) {
            int kk = it * 32 + kk0;
            short8 a0 = *(const short8*)&h1[cur][m16][kk];
            short8 a1 = *(const short8*)&h1[cur][16 + m16][kk];
            short8 a2 = *(const short8*)&h1[cur][32 + m16][kk];
            short8 a3 = *(const short8*)&h1[cur][48 + m16][kk];
            acc2[0][0] = __builtin_amdgcn_mfma_f32_16x16x32_bf16(a0, Breg[it][0], acc2[0][0], 0, 0, 0);
            acc2[1][0] = __builtin_amdgcn_mfma_f32_16x16x32_bf16(a1, Breg[it][0], acc2[1][0], 0, 0, 0);
            acc2[2][0] = __builtin_amdgcn_mfma_f32_16x16x32_bf16(a2, Breg[it][0], acc2[2][0], 0, 0, 0);
            acc2[3][0] = __builtin_amdgcn_mfma_f32_16x16x32_bf16(a3, Breg[it][0], acc2[3][0], 0, 0, 0);
            acc2[0][1] = __builtin_amdgcn_mfma_f32_16x16x32_bf16(a0, Breg[it][1], acc2[0][1], 0, 0, 0);
            acc2[1][1] = __builtin_amdgcn_mfma_f32_16x16x32_bf16(a1, Breg[it][1], acc2[1][1], 0, 0, 0);
            acc2[2][1] = __builtin_amdgcn_mfma_f32_16x16x32_bf16(a2, Breg[it][1], acc2[2][1], 0, 0, 0);
            acc2[3][1] = __builtin_amdgcn_mfma_f32_16x16x32_bf16(a3, Breg[it][1], acc2[3][1], 0, 0, 0);
        }
        if (hasNext) {
#pragma unroll
            for (int rr = 0; rr < 4; rr++) {
                int r = wave * 8 + 4 + rr;
                S8U hh;
#pragma unroll
                for (int e2 = 0; e2 < 4; e2++) {
                    float z0 = (e2 < 2) ? zA[e2 * 2] : zB[e2 * 2 - 4];
                    float z1 = (e2 < 2) ? zA[e2 * 2 + 1] : zB[e2 * 2 - 3];
                    float f0 = fmaxf(z0 + bf2f((ushort)uu[rr][e2 * 2]) + bf2f((ushort)vv[rr][e2 * 2]), 0.f);
                    float f1 = fmaxf(z1 + bf2f((ushort)uu[rr][e2 * 2 + 1]) + bf2f((ushort)vv[rr][e2 * 2 + 1]), 0.f);
                    hh.u[e2] = pk_bf16(f0, f1);
                }
                *(short8*)&h1[nxt][r][c8] = hh.s;
            }
        }

#pragma unroll
        for (int mt = 0; mt < 4; mt++)
#pragma unroll
            for (int tt = 0; tt < 4; tt++) {
                float s = 0.f;
#pragma unroll
                for (int nt = 0; nt < 2; nt++)
                    s += fmaxf(acc2[mt][nt][tt] + eb2v[nt], 0.f) * ew3v[nt];
                s += __shfl_xor(s, 1);
                s += __shfl_xor(s, 2);
                s += __shfl_xor(s, 4);
                s += __shfl_xor(s, 8);
                if (m16 == 0) part[mt * 16 + quad * 4 + tt][wave] = s;
            }
        __syncthreads();

        if (tid < MTILE) {
            int p = (ti0 + t) * MTILE + tid;
            if (p < NPAIRS) {
                float v = eb3[0];
#pragma unroll
                for (int w = 0; w < 8; w++) v += part[tid][w];
                out_edges[b * NPAIRS + p] = sigmoidf(v);
            }
        }
        __syncthreads();
    }
}

extern "C" void kernel_launch(void* const* d_in, const int* in_sizes, int n_in,
                              void* d_out, int out_size, void* d_ws, size_t ws_size,
                              hipStream_t stream) {
    const float* z   = (const float*)d_in[0];
    const float* nw1 = (const float*)d_in[1];
    const float* nb1 = (const float*)d_in[2];
    const float* nw2 = (const float*)d_in[3];
    const float* nb2 = (const float*)d_in[4];
    const float* nw3 = (const float*)d_in[5];
    const float* nb3 = (const float*)d_in[6];
    const float* ew1 = (const float*)d_in[7];
    const float* eb1 = (const float*)d_in[8];
    const float* ew2 = (const float*)d_in[9];
    const float* eb2 = (const float*)d_in[10];
    const float* ew3 = (const float*)d_in[11];
    const float* eb3 = (const float*)d_in[12];

    char* ws = (char*)d_ws;
    int*    ptab = (int*)(ws);                       // 1225*4
    ushort* h2b  = (ushort*)(ws + 262144);           // 131072
    ushort* nf   = (ushort*)(ws + 393216);           // 1638400
    ushort* ew2T = (ushort*)(ws + 2031616);          // 262144
    ushort* wijT = (ushort*)(ws + 2293760);          // 262144
    ushort* nw3T = (ushort*)(ws + 2555904);          // 6553600
    float*  Zc   = (float*)(ws + 9109504);           // 262144
    ushort* UV   = (ushort*)(ws + 9371648);          // 13107200

    float* out_nodes = (float*)d_out;                // 128*6400
    float* out_edges = out_nodes + BATCH * NODE_OUT; // 128*1225

    k_prep_all<<<PREPK_NB, 256, 0, stream>>>(nw3, nw3T, ew1, ew2, ew2T, wijT,
                                             z, eb1, Zc, nw1, nb1, nw2, nb2,
                                             h2b, ptab);
    k_node_out_mfma<<<200, 256, 0, stream>>>(h2b, nw3T, nb3, out_nodes, nf);
    k_uv<<<400, 256, 0, stream>>>(nf, wijT, UV);
    k_edge8<<<NBLK, 512, 0, stream>>>(Zc, UV, ew2T, ew3, eb2, eb3, ptab, out_edges);
}